// Round 12
// baseline (62.332 us; speedup 1.0000x reference)
//
#include <hip/hip_runtime.h>
#include <hip/hip_bf16.h>

// QLoRA SwiGLU MLP, B=16 tokens, d=4096, h=11008, r=2.
// tile(wq,(1,4)) => x @ W^T == fold4(x) @ wq^T  (skinny GEMM, K = in/4).
// R12: gateup rebuilt as LDS-staged GEMM. R10/R11 proved the compiler
// refuses >depth-1 register prefetch for direct-to-fragment global loads
// (VGPR 44->40, 2 TB/s). Staging loads (global->reg->ds_write, linear,
// coalesced, no early consumer) pipeline naturally at stream rate like the
// 6.7 TB/s fill kernel; MFMA fragments then come from LDS (padded rows).
// down/prep1 structure kept from R10/R11.

#define NB     16
#define DMODEL 4096
#define HID    11008
#define DQ     1024   // DMODEL/4
#define HQ     2752   // HID/4

// workspace layout (float offsets)
#define XSB_OFF 0         // xs bf16 [16][1024] = 8192 floats
#define T1_OFF  8192      // [16][2] f32
#define T3_OFF  8224
#define HF_OFF  8256      // hfold f32 [16][2752] = 44032 floats
#define T2_OFF  52288     // [16][2] f32  (zeroed with hfold by prep1)

#define LPAD 260          // padded LDS row stride (f32): 16B-aligned, ~2-way banks

typedef __attribute__((ext_vector_type(8))) short bf16x8;
typedef __attribute__((ext_vector_type(4))) float f32x4;

__device__ __forceinline__ unsigned short f2bfh(float f) {
  __hip_bfloat16 h = __float2bfloat16(f);   // v_cvt, RNE
  return __builtin_bit_cast(unsigned short, h);
}
__device__ __forceinline__ unsigned pack2(float lo, float hi) {
  return (unsigned)f2bfh(lo) | ((unsigned)f2bfh(hi) << 16);
}
__device__ __forceinline__ bf16x8 cvt8(const float4 a, const float4 b) {
  uint4 u = make_uint4(pack2(a.x, a.y), pack2(a.z, a.w),
                       pack2(b.x, b.y), pack2(b.z, b.w));
  return __builtin_bit_cast(bf16x8, u);
}

// ---------------------------------------------------------------------------
// prep1: 64 blocks. All blocks zero hfold/T2/out; blocks 0-15 also compute
// xs[b] = fold4(x[b]) (bf16) and t1,t3 LoRA-A dots.
__global__ __launch_bounds__(256) void k_prep1(const float* __restrict__ x,
                                               const float* __restrict__ a1,
                                               const float* __restrict__ a3,
                                               float* __restrict__ ws,
                                               float* __restrict__ out) {
  const int t = threadIdx.x;
  const int gid = blockIdx.x * 256 + t;        // 0..16383
  const float4 z4 = make_float4(0.f, 0.f, 0.f, 0.f);
  if (gid < 11016) ((float4*)(ws + HF_OFF))[gid] = z4;   // hfold + T2
  ((float4*)out)[gid] = z4;                               // out: 16384 f4
  if (blockIdx.x >= 16) return;

  const int b = blockIdx.x;
  const float4* x4  = (const float4*)(x) + b * (DMODEL / 4);
  const float4* a14 = (const float4*)a1;
  const float4* a34 = (const float4*)a3;
  float4 xs = z4;
  float s10 = 0.f, s11 = 0.f, s30 = 0.f, s31 = 0.f;
#pragma unroll
  for (int k = 0; k < 4; ++k) {
    float4 xv  = x4[k * 256 + t];
    xs.x += xv.x; xs.y += xv.y; xs.z += xv.z; xs.w += xv.w;
    float4 a10 = a14[k * 256 + t];
    float4 a11 = a14[1024 + k * 256 + t];
    float4 a30 = a34[k * 256 + t];
    float4 a31 = a34[1024 + k * 256 + t];
    s10 += xv.x * a10.x + xv.y * a10.y + xv.z * a10.z + xv.w * a10.w;
    s11 += xv.x * a11.x + xv.y * a11.y + xv.z * a11.z + xv.w * a11.w;
    s30 += xv.x * a30.x + xv.y * a30.y + xv.z * a30.z + xv.w * a30.w;
    s31 += xv.x * a31.x + xv.y * a31.y + xv.z * a31.z + xv.w * a31.w;
  }
  ((uint2*)(ws + XSB_OFF))[b * 256 + t] =
      make_uint2(pack2(xs.x, xs.y), pack2(xs.z, xs.w));

  __shared__ float4 rb[256];
  rb[t] = make_float4(s10, s11, s30, s31);
  __syncthreads();
  for (int s = 128; s > 0; s >>= 1) {
    if (t < s) {
      rb[t].x += rb[t + s].x; rb[t].y += rb[t + s].y;
      rb[t].z += rb[t + s].z; rb[t].w += rb[t + s].w;
    }
    __syncthreads();
  }
  if (t == 0) {
    ws[T1_OFF + b * 2]     = rb[0].x;
    ws[T1_OFF + b * 2 + 1] = rb[0].y;
    ws[T3_OFF + b * 2]     = rb[0].z;
    ws[T3_OFF + b * 2 + 1] = rb[0].w;
  }
}

// ---------------------------------------------------------------------------
// gateup: 688 blocks x 256 thr (4 waves). Block = 16 output rows, K=1024 in
// 4 chunks of 256. Per chunk: stage w1+w3 16x256 f32 into LDS (linear
// coalesced loads, 8 f4/thread), then wave w = K-quarter does 2 kk x 2 MFMA
// from LDS. Cross-wave reduce in LDS (reused); fused LoRA/silu/atomic-fold.
__global__ __launch_bounds__(256) void k_gateup(const float* __restrict__ w1q,
                                                const float* __restrict__ w3q,
                                                const float* __restrict__ b1,
                                                const float* __restrict__ b3,
                                                const float* __restrict__ a2,
                                                float* __restrict__ ws) {
  __shared__ float smem[2 * 16 * LPAD];   // 33.3 KB; reused for reduce
  const int t = threadIdx.x, w = t >> 6, l = t & 63;
  const int row0 = blockIdx.x * 16;
  const int n  = l & 15;
  const int kb = (l >> 4) * 8;
  const unsigned short* xsb = (const unsigned short*)(ws + XSB_OFF);

  f32x4 acc1 = {0.f, 0.f, 0.f, 0.f}, acc3 = {0.f, 0.f, 0.f, 0.f};

  for (int c = 0; c < 4; ++c) {
    // stage: 2 matrices x 16 rows x 64 float4 = 2048 f4 over 256 thr = 8 it
#pragma unroll
    for (int it = 0; it < 8; ++it) {
      const int i = it * 256 + t;
      const int m = i >> 10, rem = i & 1023;
      const int row = rem >> 6, col = rem & 63;
      const float* src = m ? w3q : w1q;
      const float4 v = *(const float4*)(src + (size_t)(row0 + row) * DQ +
                                        c * 256 + col * 4);
      *(float4*)(smem + m * (16 * LPAD) + row * LPAD + col * 4) = v;
    }
    __syncthreads();
    // compute: wave w owns K-quarter [w*64, w*64+64) of this chunk
#pragma unroll
    for (int j = 0; j < 2; ++j) {
      const int kloc = (w * 2 + j) * 32 + kb;        // 0..255 in-chunk
      const float* a1p = smem + n * LPAD + kloc;
      const float* a3p = smem + 16 * LPAD + n * LPAD + kloc;
      const float4 a1a = *(const float4*)(a1p);
      const float4 a1b = *(const float4*)(a1p + 4);
      const float4 a3a = *(const float4*)(a3p);
      const float4 a3b = *(const float4*)(a3p + 4);
      const bf16x8 bb = *(const bf16x8*)(xsb + n * DQ + c * 256 + kloc);
      acc1 = __builtin_amdgcn_mfma_f32_16x16x32_bf16(cvt8(a1a, a1b), bb,
                                                     acc1, 0, 0, 0);
      acc3 = __builtin_amdgcn_mfma_f32_16x16x32_bf16(cvt8(a3a, a3b), bb,
                                                     acc3, 0, 0, 0);
    }
    __syncthreads();
  }

  // cross-wave K-reduce via LDS (safe to overwrite after last barrier)
  float* red = smem;                       // [w][8][64] = 2048 floats
#pragma unroll
  for (int r = 0; r < 4; ++r) {
    red[(w * 8 + r) * 64 + l]     = acc1[r];
    red[(w * 8 + r + 4) * 64 + l] = acc3[r];
  }
  __syncthreads();
  if (w == 0) {
    const float t10 = ws[T1_OFF + 2 * n], t11 = ws[T1_OFF + 2 * n + 1];
    const float t30 = ws[T3_OFF + 2 * n], t31 = ws[T3_OFF + 2 * n + 1];
    const int m4 = (l >> 4) * 4;
    float s0 = 0.f, s1 = 0.f;              // t2 partials for token n
#pragma unroll
    for (int r = 0; r < 4; ++r) {
      float g0 = 0.f, u0 = 0.f;
#pragma unroll
      for (int ww = 0; ww < 4; ++ww) {
        g0 += red[(ww * 8 + r) * 64 + l];
        u0 += red[(ww * 8 + r + 4) * 64 + l];
      }
      const int oo = row0 + m4 + r;
      const float g = g0 + 0.5f * (t10 * b1[2 * oo] + t11 * b1[2 * oo + 1]);
      const float u = u0 + 0.5f * (t30 * b3[2 * oo] + t31 * b3[2 * oo + 1]);
      const float v = (g / (1.f + __expf(-g))) * u;
      atomicAdd(&ws[HF_OFF + n * HQ + (oo % HQ)], v);
      s0 += v * a2[oo];
      s1 += v * a2[HID + oo];
    }
    s0 += __shfl_xor(s0, 16);  s0 += __shfl_xor(s0, 32);
    s1 += __shfl_xor(s1, 16);  s1 += __shfl_xor(s1, 32);
    if (l < 16) {
      atomicAdd(&ws[T2_OFF + 2 * n], s0);
      atomicAdd(&ws[T2_OFF + 2 * n + 1], s1);
    }
  }
}

// ---------------------------------------------------------------------------
// down: 512 blocks x 256 thr (4 waves). Block = (tile, K-half); global wave
// g = half*4+w covers kk {11x6,10x2} of K=2752. 4-set 1-kk rolling pipeline.
#define SB __builtin_amdgcn_sched_barrier(0)

#define DN_PF(KK, WA, WB, HA, HB) do {                                      \
    const int _ka = (kks + (KK)) * 32 + kb;                                 \
    const float4* _p2 = (const float4*)(w2q + (size_t)o * HQ + _ka);        \
    const float4* _pb = (const float4*)(hf + (size_t)n * HQ + _ka);         \
    WA = _p2[0]; WB = _p2[1]; HA = _pb[0]; HB = _pb[1];                     \
  } while (0)

#define DN_MM(WA, WB, HA, HB)                                               \
  acc = __builtin_amdgcn_mfma_f32_16x16x32_bf16(cvt8(WA, WB),               \
                                                cvt8(HA, HB), acc, 0, 0, 0)

__global__ __launch_bounds__(256) void k_down(const float* __restrict__ w2q,
                                              const float* __restrict__ b2,
                                              const float* __restrict__ ws,
                                              float* __restrict__ out) {
  __shared__ float red[4][4][64];
  const int t = threadIdx.x, w = t >> 6, l = t & 63;
  const int tile = blockIdx.x >> 1, half = blockIdx.x & 1;
  const int g = half * 4 + w;
  const int n  = l & 15;
  const int kb = (l >> 4) * 8;
  const int o  = tile * 16 + n;
  const float* hf = ws + HF_OFF;
  const int kks  = (g < 6) ? g * 11 : 66 + (g - 6) * 10;
  const int klen = (g < 6) ? 11 : 10;

  f32x4 acc = {0.f, 0.f, 0.f, 0.f};
  float4 w0a, w0b, h0a, h0b;
  float4 w1a, w1b, h1a, h1b;
  float4 w2a, w2b, h2a, h2b;
  float4 w3a, w3b, h3a, h3b;

  DN_PF(0, w0a, w0b, h0a, h0b);
  DN_PF(1, w1a, w1b, h1a, h1b);
  DN_PF(2, w2a, w2b, h2a, h2b);
  DN_PF(3, w3a, w3b, h3a, h3b);
  SB;
  DN_MM(w0a, w0b, h0a, h0b);  DN_PF(4, w0a, w0b, h0a, h0b);  SB;
  DN_MM(w1a, w1b, h1a, h1b);  DN_PF(5, w1a, w1b, h1a, h1b);  SB;
  DN_MM(w2a, w2b, h2a, h2b);  DN_PF(6, w2a, w2b, h2a, h2b);  SB;
  DN_MM(w3a, w3b, h3a, h3b);  DN_PF(7, w3a, w3b, h3a, h3b);  SB;
  DN_MM(w0a, w0b, h0a, h0b);  DN_PF(8, w0a, w0b, h0a, h0b);  SB;
  DN_MM(w1a, w1b, h1a, h1b);  DN_PF(9, w1a, w1b, h1a, h1b);  SB;
  DN_MM(w2a, w2b, h2a, h2b);
  if (klen > 10) { DN_PF(10, w2a, w2b, h2a, h2b); }
  SB;
  DN_MM(w3a, w3b, h3a, h3b);
  DN_MM(w0a, w0b, h0a, h0b);
  DN_MM(w1a, w1b, h1a, h1b);
  if (klen > 10) { DN_MM(w2a, w2b, h2a, h2b); }

#pragma unroll
  for (int r = 0; r < 4; ++r) red[w][r][l] = acc[r];
  __syncthreads();
  if (w == 0) {
    const float t20 = ws[T2_OFF + 2 * n], t21 = ws[T2_OFF + 2 * n + 1];
    const int m4 = (l >> 4) * 4;
#pragma unroll
    for (int r = 0; r < 4; ++r) {
      float v = red[0][r][l] + red[1][r][l] + red[2][r][l] + red[3][r][l];
      const int oo = tile * 16 + m4 + r;
      if (half == 0)
        v += 0.5f * (t20 * b2[2 * oo] + t21 * b2[2 * oo + 1]);
      atomicAdd(&out[n * DMODEL + oo], v);
    }
  }
}

// ---------------------------------------------------------------------------
extern "C" void kernel_launch(void* const* d_in, const int* in_sizes, int n_in,
                              void* d_out, int out_size, void* d_ws, size_t ws_size,
                              hipStream_t stream) {
  const float* x   = (const float*)d_in[0];
  const float* w1q = (const float*)d_in[1];
  const float* a1  = (const float*)d_in[2];
  const float* b1  = (const float*)d_in[3];
  const float* w3q = (const float*)d_in[4];
  const float* a3  = (const float*)d_in[5];
  const float* b3  = (const float*)d_in[6];
  const float* w2q = (const float*)d_in[7];
  const float* a2  = (const float*)d_in[8];
  const float* b2  = (const float*)d_in[9];
  float* out = (float*)d_out;
  float* ws  = (float*)d_ws;

  k_prep1<<<64, 256, 0, stream>>>(x, a1, a3, ws, out);
  k_gateup<<<HID / 16, 256, 0, stream>>>(w1q, w3q, b1, b3, a2, ws);
  k_down<<<2 * (DMODEL / 16), 256, 0, stream>>>(w2q, b2, ws, out);
}

// Round 13
// 61.380 us; speedup vs baseline: 1.0155x; 1.0155x over previous
//
#include <hip/hip_runtime.h>
#include <hip/hip_bf16.h>

// QLoRA SwiGLU MLP, B=16 tokens, d=4096, h=11008, r=2.
// tile(wq,(1,4)) => x @ W^T == fold4(x) @ wq^T  (skinny GEMM, K = in/4).
// R13: global_load_lds DMA staging. R10/R11/R12 all showed hipcc collapses
// any load-to-VGPR pipeline to depth ~1 (VGPR 44/40/52 -> 2 TB/s). DMA
// global->LDS has no result registers -> nothing to serialize. Wave-local
// K-ranges, 2x8KB LDS buffers/wave, counted s_waitcnt vmcnt(8) (never 0
// until end), LDS laid out [unit][row] so fragment ds_reads are ~2-way.
// Epilogues identical to R12 (passing).

#define NB     16
#define DMODEL 4096
#define HID    11008
#define DQ     1024   // DMODEL/4
#define HQ     2752   // HID/4

// workspace layout (float offsets)
#define XSB_OFF 0         // xs bf16 [16][1024] = 8192 floats
#define T1_OFF  8192      // [16][2] f32
#define T3_OFF  8224
#define HF_OFF  8256      // hfold f32 [16][2752] = 44032 floats
#define T2_OFF  52288     // [16][2] f32  (zeroed with hfold by prep1)

typedef __attribute__((ext_vector_type(8))) short bf16x8;
typedef __attribute__((ext_vector_type(4))) float f32x4;

__device__ __forceinline__ unsigned short f2bfh(float f) {
  __hip_bfloat16 h = __float2bfloat16(f);   // v_cvt, RNE
  return __builtin_bit_cast(unsigned short, h);
}
__device__ __forceinline__ unsigned pack2(float lo, float hi) {
  return (unsigned)f2bfh(lo) | ((unsigned)f2bfh(hi) << 16);
}
__device__ __forceinline__ bf16x8 cvt8(const float4 a, const float4 b) {
  uint4 u = make_uint4(pack2(a.x, a.y), pack2(a.z, a.w),
                       pack2(b.x, b.y), pack2(b.z, b.w));
  return __builtin_bit_cast(bf16x8, u);
}
__device__ __forceinline__ void gload_lds16(const float* g, float* l) {
  __builtin_amdgcn_global_load_lds(
      (const __attribute__((address_space(1))) void*)g,
      (__attribute__((address_space(3))) void*)l, 16, 0, 0);
}

#define SB       __builtin_amdgcn_sched_barrier(0)
#define WAITV(N) asm volatile("s_waitcnt vmcnt(" #N ")" ::: "memory")
#define WAITL    asm volatile("s_waitcnt lgkmcnt(0)" ::: "memory")

// ---------------------------------------------------------------------------
// prep1: 64 blocks. All blocks zero hfold/T2/out; blocks 0-15 also compute
// xs[b] = fold4(x[b]) (bf16) and t1,t3 LoRA-A dots.
__global__ __launch_bounds__(256) void k_prep1(const float* __restrict__ x,
                                               const float* __restrict__ a1,
                                               const float* __restrict__ a3,
                                               float* __restrict__ ws,
                                               float* __restrict__ out) {
  const int t = threadIdx.x;
  const int gid = blockIdx.x * 256 + t;        // 0..16383
  const float4 z4 = make_float4(0.f, 0.f, 0.f, 0.f);
  if (gid < 11016) ((float4*)(ws + HF_OFF))[gid] = z4;   // hfold + T2
  ((float4*)out)[gid] = z4;                               // out: 16384 f4
  if (blockIdx.x >= 16) return;

  const int b = blockIdx.x;
  const float4* x4  = (const float4*)(x) + b * (DMODEL / 4);
  const float4* a14 = (const float4*)a1;
  const float4* a34 = (const float4*)a3;
  float4 xs = z4;
  float s10 = 0.f, s11 = 0.f, s30 = 0.f, s31 = 0.f;
#pragma unroll
  for (int k = 0; k < 4; ++k) {
    float4 xv  = x4[k * 256 + t];
    xs.x += xv.x; xs.y += xv.y; xs.z += xv.z; xs.w += xv.w;
    float4 a10 = a14[k * 256 + t];
    float4 a11 = a14[1024 + k * 256 + t];
    float4 a30 = a34[k * 256 + t];
    float4 a31 = a34[1024 + k * 256 + t];
    s10 += xv.x * a10.x + xv.y * a10.y + xv.z * a10.z + xv.w * a10.w;
    s11 += xv.x * a11.x + xv.y * a11.y + xv.z * a11.z + xv.w * a11.w;
    s30 += xv.x * a30.x + xv.y * a30.y + xv.z * a30.z + xv.w * a30.w;
    s31 += xv.x * a31.x + xv.y * a31.y + xv.z * a31.z + xv.w * a31.w;
  }
  ((uint2*)(ws + XSB_OFF))[b * 256 + t] =
      make_uint2(pack2(xs.x, xs.y), pack2(xs.z, xs.w));

  __shared__ float4 rb[256];
  rb[t] = make_float4(s10, s11, s30, s31);
  __syncthreads();
  for (int s = 128; s > 0; s >>= 1) {
    if (t < s) {
      rb[t].x += rb[t + s].x; rb[t].y += rb[t + s].y;
      rb[t].z += rb[t + s].z; rb[t].w += rb[t + s].w;
    }
    __syncthreads();
  }
  if (t == 0) {
    ws[T1_OFF + b * 2]     = rb[0].x;
    ws[T1_OFF + b * 2 + 1] = rb[0].y;
    ws[T3_OFF + b * 2]     = rb[0].z;
    ws[T3_OFF + b * 2 + 1] = rb[0].w;
  }
}

// ---------------------------------------------------------------------------
// gateup: 688 blocks x 256 thr (4 waves). Tile = 16 rows; wave w owns
// K-quarter [w*256,w*256+256) of both matrices. DMA chunks of 128 f32/row
// (8 KB) into [32 unit][16 row] LDS layout; rolling 2-buffer counted-vmcnt.
#define GU_ISSUE(MATP, E, BUF) do {                                         \
    _Pragma("unroll")                                                       \
    for (int _i = 0; _i < 8; ++_i) {                                        \
      const float* _src = (MATP) + (size_t)(row0 + n) * DQ + w * 256 +      \
                          (E) * 128 + (_i * 4 + g) * 4;                     \
      gload_lds16(_src, (float*)(ldsv + w4 + (BUF) * 512 + _i * 64));       \
    }                                                                       \
  } while (0)

#define GU_COMP(BUF, ACC, KO) do {                                          \
    _Pragma("unroll")                                                       \
    for (int _kk = 0; _kk < 4; ++_kk) {                                     \
      const int _u0 = _kk * 8 + 2 * g;                                      \
      const float4 _a  = *(const float4*)(ldsv + w4 + (BUF) * 512 +         \
                                          _u0 * 16 + n);                    \
      const float4 _b2 = *(const float4*)(ldsv + w4 + (BUF) * 512 +         \
                                          (_u0 + 1) * 16 + n);              \
      ACC = __builtin_amdgcn_mfma_f32_16x16x32_bf16(cvt8(_a, _b2),          \
                bb[(KO) + _kk], ACC, 0, 0, 0);                              \
    }                                                                       \
  } while (0)

__global__ __launch_bounds__(256) void k_gateup(const float* __restrict__ w1q,
                                                const float* __restrict__ w3q,
                                                const float* __restrict__ b1,
                                                const float* __restrict__ b3,
                                                const float* __restrict__ a2,
                                                float* __restrict__ ws) {
  __shared__ float4 ldsv[4096];   // 64 KB: wave w owns f4 [w*1024, +1024)
  __shared__ float red[2048];     // 8 KB cross-wave reduce
  const int t = threadIdx.x, w = t >> 6, l = t & 63;
  const int row0 = blockIdx.x * 16;
  const int n = l & 15, g = l >> 4, kb = g * 8;
  const int w4 = w * 1024;
  const unsigned short* xsb = (const unsigned short*)(ws + XSB_OFF);

  // B-fragments: lane's 8 bf16 per kk, whole K-quarter, reused for w1 & w3.
  bf16x8 bb[8];
#pragma unroll
  for (int q = 0; q < 8; ++q)
    bb[q] = *(const bf16x8*)(xsb + n * DQ + w * 256 + q * 32 + kb);
  SB;
  GU_ISSUE(w1q, 0, 0); SB;
  GU_ISSUE(w1q, 1, 1); SB;

  f32x4 acc1 = {0.f, 0.f, 0.f, 0.f}, acc3 = {0.f, 0.f, 0.f, 0.f};
  WAITV(8); SB;                   // bb(8)+w1e0(8) retired; w1e1 in flight
  GU_COMP(0, acc1, 0);
  WAITL; SB;
  GU_ISSUE(w3q, 0, 0); SB;        // overwrite buf0 after its reads retired
  WAITV(8); SB;                   // w1e1 done; w3e0 in flight
  GU_COMP(1, acc1, 4);
  WAITL; SB;
  GU_ISSUE(w3q, 1, 1); SB;
  WAITV(8); SB;                   // w3e0 done
  GU_COMP(0, acc3, 0);
  WAITV(0); SB;                   // w3e1 done
  GU_COMP(1, acc3, 4);

#pragma unroll
  for (int r = 0; r < 4; ++r) {
    red[(w * 8 + r) * 64 + l]     = acc1[r];
    red[(w * 8 + r + 4) * 64 + l] = acc3[r];
  }
  __syncthreads();
  if (w == 0) {
    const float t10 = ws[T1_OFF + 2 * n], t11 = ws[T1_OFF + 2 * n + 1];
    const float t30 = ws[T3_OFF + 2 * n], t31 = ws[T3_OFF + 2 * n + 1];
    const int m4 = g * 4;
    float s0 = 0.f, s1 = 0.f;     // t2 partials for token n
#pragma unroll
    for (int r = 0; r < 4; ++r) {
      float g0 = 0.f, u0 = 0.f;
#pragma unroll
      for (int ww = 0; ww < 4; ++ww) {
        g0 += red[(ww * 8 + r) * 64 + l];
        u0 += red[(ww * 8 + r + 4) * 64 + l];
      }
      const int oo = row0 + m4 + r;
      const float gg = g0 + 0.5f * (t10 * b1[2 * oo] + t11 * b1[2 * oo + 1]);
      const float uu = u0 + 0.5f * (t30 * b3[2 * oo] + t31 * b3[2 * oo + 1]);
      const float v = (gg / (1.f + __expf(-gg))) * uu;
      atomicAdd(&ws[HF_OFF + n * HQ + (oo % HQ)], v);
      s0 += v * a2[oo];
      s1 += v * a2[HID + oo];
    }
    s0 += __shfl_xor(s0, 16);  s0 += __shfl_xor(s0, 32);
    s1 += __shfl_xor(s1, 16);  s1 += __shfl_xor(s1, 32);
    if (l < 16) {
      atomicAdd(&ws[T2_OFF + 2 * n], s0);
      atomicAdd(&ws[T2_OFF + 2 * n + 1], s1);
    }
  }
}

// ---------------------------------------------------------------------------
// down: 512 blocks x 256 thr (4 waves). Block = (tile 16 rows, K-half of
// 43 kk); waves take {12,11,10,10} kk in 3 chunks of 4. w2 via DMA chunks,
// hf B-frags direct (L3-resident). Partial chunk wave-uniform-guarded.
#define DN_ISSUE(CB, BUF) do {                                              \
    _Pragma("unroll")                                                       \
    for (int _i = 0; _i < 8; ++_i) {                                        \
      const float* _src = w2q + (size_t)(row0 + n) * HQ +                   \
                          (hbase + (CB)) * 32 + (_i * 4 + g) * 4;           \
      gload_lds16(_src, (float*)(ldsv + w4 + (BUF) * 512 + _i * 64));       \
    }                                                                       \
  } while (0)

#define DN_HF(CB, H) do {                                                   \
    _Pragma("unroll")                                                       \
    for (int _k = 0; _k < 4; ++_k) {                                        \
      const float* _p = hf + (size_t)n * HQ + (hbase + (CB) + _k) * 32 + kb;\
      H[2 * _k]     = *(const float4*)_p;                                   \
      H[2 * _k + 1] = *(const float4*)(_p + 4);                             \
    }                                                                       \
  } while (0)

#define DN_COMP(CB, BUF, H, LO, HI) do {                                    \
    _Pragma("unroll")                                                       \
    for (int _kk = 0; _kk < 4; ++_kk) {                                     \
      if ((CB) + _kk >= (LO) && (CB) + _kk < (HI)) {                        \
        const int _u0 = _kk * 8 + 2 * g;                                    \
        const float4 _a  = *(const float4*)(ldsv + w4 + (BUF) * 512 +       \
                                            _u0 * 16 + n);                  \
        const float4 _b2 = *(const float4*)(ldsv + w4 + (BUF) * 512 +       \
                                            (_u0 + 1) * 16 + n);            \
        acc = __builtin_amdgcn_mfma_f32_16x16x32_bf16(cvt8(_a, _b2),        \
                  cvt8(H[2 * _kk], H[2 * _kk + 1]), acc, 0, 0, 0);          \
      }                                                                     \
    }                                                                       \
  } while (0)

__global__ __launch_bounds__(256) void k_down(const float* __restrict__ w2q,
                                              const float* __restrict__ b2,
                                              const float* __restrict__ ws,
                                              float* __restrict__ out) {
  __shared__ float4 ldsv[4096];
  __shared__ float red[1024];
  const int t = threadIdx.x, w = t >> 6, l = t & 63;
  const int tile = blockIdx.x >> 1, half = blockIdx.x & 1;
  const int row0 = tile * 16;
  const int hbase = half * 43;
  const int n = l & 15, g = l >> 4, kb = g * 8;
  const int w4 = w * 1024;
  const float* hf = ws + HF_OFF;

  const int wstart = (w == 0) ? 0 : (w == 1) ? 12 : (w == 2) ? 23 : 33;
  const int vlen   = (w == 0) ? 12 : (w == 1) ? 11 : 10;
  const int cb0 = wstart, cb1 = wstart + 4;
  const int cb2t = wstart + 8;
  const int cb2 = (cb2t > 39) ? 39 : cb2t;     // clamp staging in-bounds
  const int hi2 = wstart + vlen;

  f32x4 acc = {0.f, 0.f, 0.f, 0.f};
  float4 h0[8], h1[8], h2[8];

  DN_ISSUE(cb0, 0); SB;
  DN_HF(cb0, h0);   SB;
  DN_ISSUE(cb1, 1); SB;
  DN_HF(cb1, h1);   SB;
  WAITV(16); SB;                  // DMA0 + hf0 retired
  DN_COMP(cb0, 0, h0, 0, 9999);
  WAITL; SB;
  DN_ISSUE(cb2, 0); SB;
  DN_HF(cb2, h2);   SB;
  WAITV(16); SB;                  // DMA1 + hf1 retired
  DN_COMP(cb1, 1, h1, 0, 9999);
  WAITV(0); SB;
  DN_COMP(cb2, 0, h2, cb2t, hi2);

#pragma unroll
  for (int r = 0; r < 4; ++r) red[(w * 4 + r) * 64 + l] = acc[r];
  __syncthreads();
  if (w == 0) {
    const float t20 = ws[T2_OFF + 2 * n], t21 = ws[T2_OFF + 2 * n + 1];
    const int m4 = g * 4;
#pragma unroll
    for (int r = 0; r < 4; ++r) {
      float v = red[r * 64 + l] + red[(4 + r) * 64 + l] +
                red[(8 + r) * 64 + l] + red[(12 + r) * 64 + l];
      const int oo = row0 + m4 + r;
      if (half == 0)
        v += 0.5f * (t20 * b2[2 * oo] + t21 * b2[2 * oo + 1]);
      atomicAdd(&out[n * DMODEL + oo], v);
    }
  }
}

// ---------------------------------------------------------------------------
extern "C" void kernel_launch(void* const* d_in, const int* in_sizes, int n_in,
                              void* d_out, int out_size, void* d_ws, size_t ws_size,
                              hipStream_t stream) {
  const float* x   = (const float*)d_in[0];
  const float* w1q = (const float*)d_in[1];
  const float* a1  = (const float*)d_in[2];
  const float* b1  = (const float*)d_in[3];
  const float* w3q = (const float*)d_in[4];
  const float* a3  = (const float*)d_in[5];
  const float* b3  = (const float*)d_in[6];
  const float* w2q = (const float*)d_in[7];
  const float* a2  = (const float*)d_in[8];
  const float* b2  = (const float*)d_in[9];
  float* out = (float*)d_out;
  float* ws  = (float*)d_ws;

  k_prep1<<<64, 256, 0, stream>>>(x, a1, a3, ws, out);
  k_gateup<<<HID / 16, 256, 0, stream>>>(w1q, w3q, b1, b3, a2, ws);
  k_down<<<512, 256, 0, stream>>>(w2q, b2, ws, out);
}

// Round 14
// 56.501 us; speedup vs baseline: 1.1032x; 1.0864x over previous
//
#include <hip/hip_runtime.h>
#include <hip/hip_bf16.h>

// QLoRA SwiGLU MLP, B=16 tokens, d=4096, h=11008, r=2.
// tile(wq,(1,4)) => x @ W^T == fold4(x) @ wq^T  (skinny GEMM, K = in/4).
// R14: gateup converges to the m97-proven staging recipe: block-cooperative
// global_load_lds with LINEAR per-instruction sources (64 lanes = one
// contiguous 1KB row segment; R13's lane-scattered sources = 16 L2
// transactions/instr was the deviation), padded LDS [2][16][260] double
// buffer, plain __syncthreads schedule stage(c+1) || compute(c).
// down/prep1/epilogues identical to R13 (passing, down ~7-8us at 5+ TB/s).

#define NB     16
#define DMODEL 4096
#define HID    11008
#define DQ     1024   // DMODEL/4
#define HQ     2752   // HID/4

// workspace layout (float offsets)
#define XSB_OFF 0         // xs bf16 [16][1024] = 8192 floats
#define T1_OFF  8192      // [16][2] f32
#define T3_OFF  8224
#define HF_OFF  8256      // hfold f32 [16][2752] = 44032 floats
#define T2_OFF  52288     // [16][2] f32  (zeroed with hfold by prep1)

typedef __attribute__((ext_vector_type(8))) short bf16x8;
typedef __attribute__((ext_vector_type(4))) float f32x4;

__device__ __forceinline__ unsigned short f2bfh(float f) {
  __hip_bfloat16 h = __float2bfloat16(f);   // v_cvt, RNE
  return __builtin_bit_cast(unsigned short, h);
}
__device__ __forceinline__ unsigned pack2(float lo, float hi) {
  return (unsigned)f2bfh(lo) | ((unsigned)f2bfh(hi) << 16);
}
__device__ __forceinline__ bf16x8 cvt8(const float4 a, const float4 b) {
  uint4 u = make_uint4(pack2(a.x, a.y), pack2(a.z, a.w),
                       pack2(b.x, b.y), pack2(b.z, b.w));
  return __builtin_bit_cast(bf16x8, u);
}
__device__ __forceinline__ void gload_lds16(const float* g, float* l) {
  __builtin_amdgcn_global_load_lds(
      (const __attribute__((address_space(1))) void*)g,
      (__attribute__((address_space(3))) void*)l, 16, 0, 0);
}

#define SB       __builtin_amdgcn_sched_barrier(0)
#define WAITV(N) asm volatile("s_waitcnt vmcnt(" #N ")" ::: "memory")
#define WAITL    asm volatile("s_waitcnt lgkmcnt(0)" ::: "memory")

// ---------------------------------------------------------------------------
// prep1: 64 blocks. All blocks zero hfold/T2/out; blocks 0-15 also compute
// xs[b] = fold4(x[b]) (bf16) and t1,t3 LoRA-A dots.
__global__ __launch_bounds__(256) void k_prep1(const float* __restrict__ x,
                                               const float* __restrict__ a1,
                                               const float* __restrict__ a3,
                                               float* __restrict__ ws,
                                               float* __restrict__ out) {
  const int t = threadIdx.x;
  const int gid = blockIdx.x * 256 + t;        // 0..16383
  const float4 z4 = make_float4(0.f, 0.f, 0.f, 0.f);
  if (gid < 11016) ((float4*)(ws + HF_OFF))[gid] = z4;   // hfold + T2
  ((float4*)out)[gid] = z4;                               // out: 16384 f4
  if (blockIdx.x >= 16) return;

  const int b = blockIdx.x;
  const float4* x4  = (const float4*)(x) + b * (DMODEL / 4);
  const float4* a14 = (const float4*)a1;
  const float4* a34 = (const float4*)a3;
  float4 xs = z4;
  float s10 = 0.f, s11 = 0.f, s30 = 0.f, s31 = 0.f;
#pragma unroll
  for (int k = 0; k < 4; ++k) {
    float4 xv  = x4[k * 256 + t];
    xs.x += xv.x; xs.y += xv.y; xs.z += xv.z; xs.w += xv.w;
    float4 a10 = a14[k * 256 + t];
    float4 a11 = a14[1024 + k * 256 + t];
    float4 a30 = a34[k * 256 + t];
    float4 a31 = a34[1024 + k * 256 + t];
    s10 += xv.x * a10.x + xv.y * a10.y + xv.z * a10.z + xv.w * a10.w;
    s11 += xv.x * a11.x + xv.y * a11.y + xv.z * a11.z + xv.w * a11.w;
    s30 += xv.x * a30.x + xv.y * a30.y + xv.z * a30.z + xv.w * a30.w;
    s31 += xv.x * a31.x + xv.y * a31.y + xv.z * a31.z + xv.w * a31.w;
  }
  ((uint2*)(ws + XSB_OFF))[b * 256 + t] =
      make_uint2(pack2(xs.x, xs.y), pack2(xs.z, xs.w));

  __shared__ float4 rb[256];
  rb[t] = make_float4(s10, s11, s30, s31);
  __syncthreads();
  for (int s = 128; s > 0; s >>= 1) {
    if (t < s) {
      rb[t].x += rb[t + s].x; rb[t].y += rb[t + s].y;
      rb[t].z += rb[t + s].z; rb[t].w += rb[t + s].w;
    }
    __syncthreads();
  }
  if (t == 0) {
    ws[T1_OFF + b * 2]     = rb[0].x;
    ws[T1_OFF + b * 2 + 1] = rb[0].y;
    ws[T3_OFF + b * 2]     = rb[0].z;
    ws[T3_OFF + b * 2 + 1] = rb[0].w;
  }
}

// ---------------------------------------------------------------------------
// gateup: 688 blocks x 256 thr (4 waves). Block = 16 rows of w1 AND w3;
// K=1024 in 4 chunks of 256 f32. Staging: 32 linear 1KB DMA per chunk-pair
// (wave w issues 8; instruction q = w*8+i -> mat q>>4, row q&15), into
// padded LDS [buf][mat][16][260]. Compute: wave w does kk = w*2+j (j=0,1)
// per chunk x 2 matrices. m97 schedule; cross-wave LDS reduce; R13 epilogue.
#define GU_STAGE(C, B) do {                                                 \
    _Pragma("unroll")                                                       \
    for (int _i = 0; _i < 8; ++_i) {                                        \
      const int _q = w * 8 + _i;                                            \
      const int _mat = _q >> 4, _row = _q & 15;                             \
      const float* _src = (_mat ? w3q : w1q) +                              \
          (size_t)(row0 + _row) * DQ + (C) * 256 + (l << 2);                \
      float* _dst = smem + (B) * 8320 + _mat * 4160 + _row * 260;           \
      gload_lds16(_src, _dst);                                              \
    }                                                                       \
  } while (0)

#define GU_COMP(C, B) do {                                                  \
    _Pragma("unroll")                                                       \
    for (int _j = 0; _j < 2; ++_j) {                                        \
      const int _kloc = (w * 2 + _j) * 32 + g * 8;                          \
      const float* _p1 = smem + (B) * 8320 + n * 260 + _kloc;               \
      const float* _p3 = _p1 + 4160;                                        \
      const float4 _a1 = *(const float4*)_p1;                               \
      const float4 _b1 = *(const float4*)(_p1 + 4);                         \
      const float4 _a3 = *(const float4*)_p3;                               \
      const float4 _b3 = *(const float4*)(_p3 + 4);                         \
      acc1 = __builtin_amdgcn_mfma_f32_16x16x32_bf16(cvt8(_a1, _b1),        \
                 bb[(C) * 2 + _j], acc1, 0, 0, 0);                          \
      acc3 = __builtin_amdgcn_mfma_f32_16x16x32_bf16(cvt8(_a3, _b3),        \
                 bb[(C) * 2 + _j], acc3, 0, 0, 0);                          \
    }                                                                       \
  } while (0)

__global__ __launch_bounds__(256) void k_gateup(const float* __restrict__ w1q,
                                                const float* __restrict__ w3q,
                                                const float* __restrict__ b1,
                                                const float* __restrict__ b3,
                                                const float* __restrict__ a2,
                                                float* __restrict__ ws) {
  __shared__ float smem[16640];   // 2 buf x 2 mat x 16 rows x 260 f32 = 65KB
  __shared__ float red[2048];     // 8 KB cross-wave reduce
  const int t = threadIdx.x, w = t >> 6, l = t & 63;
  const int row0 = blockIdx.x * 16;
  const int n = l & 15, g = l >> 4;
  const unsigned short* xsb = (const unsigned short*)(ws + XSB_OFF);

  // B-fragments for this wave's kk slots across all 4 chunks (L2-hot xs).
  bf16x8 bb[8];
#pragma unroll
  for (int p = 0; p < 8; ++p) {
    const int c = p >> 1, j = p & 1;
    bb[p] = *(const bf16x8*)(xsb + n * DQ + c * 256 + (w * 2 + j) * 32 + g * 8);
  }

  f32x4 acc1 = {0.f, 0.f, 0.f, 0.f}, acc3 = {0.f, 0.f, 0.f, 0.f};

  GU_STAGE(0, 0);
  __syncthreads();
  GU_STAGE(1, 1);  GU_COMP(0, 0);
  __syncthreads();
  GU_STAGE(2, 0);  GU_COMP(1, 1);
  __syncthreads();
  GU_STAGE(3, 1);  GU_COMP(2, 0);
  __syncthreads();
  GU_COMP(3, 1);

#pragma unroll
  for (int r = 0; r < 4; ++r) {
    red[(w * 8 + r) * 64 + l]     = acc1[r];
    red[(w * 8 + r + 4) * 64 + l] = acc3[r];
  }
  __syncthreads();
  if (w == 0) {
    const float t10 = ws[T1_OFF + 2 * n], t11 = ws[T1_OFF + 2 * n + 1];
    const float t30 = ws[T3_OFF + 2 * n], t31 = ws[T3_OFF + 2 * n + 1];
    const int m4 = g * 4;
    float s0 = 0.f, s1 = 0.f;     // t2 partials for token n
#pragma unroll
    for (int r = 0; r < 4; ++r) {
      float g0 = 0.f, u0 = 0.f;
#pragma unroll
      for (int ww = 0; ww < 4; ++ww) {
        g0 += red[(ww * 8 + r) * 64 + l];
        u0 += red[(ww * 8 + r + 4) * 64 + l];
      }
      const int oo = row0 + m4 + r;
      const float gg = g0 + 0.5f * (t10 * b1[2 * oo] + t11 * b1[2 * oo + 1]);
      const float uu = u0 + 0.5f * (t30 * b3[2 * oo] + t31 * b3[2 * oo + 1]);
      const float v = (gg / (1.f + __expf(-gg))) * uu;
      atomicAdd(&ws[HF_OFF + n * HQ + (oo % HQ)], v);
      s0 += v * a2[oo];
      s1 += v * a2[HID + oo];
    }
    s0 += __shfl_xor(s0, 16);  s0 += __shfl_xor(s0, 32);
    s1 += __shfl_xor(s1, 16);  s1 += __shfl_xor(s1, 32);
    if (l < 16) {
      atomicAdd(&ws[T2_OFF + 2 * n], s0);
      atomicAdd(&ws[T2_OFF + 2 * n + 1], s1);
    }
  }
}

// ---------------------------------------------------------------------------
// down: 512 blocks x 256 thr (4 waves), identical to R13 (passing, ~5 TB/s).
#define DN_ISSUE(CB, BUF) do {                                              \
    _Pragma("unroll")                                                       \
    for (int _i = 0; _i < 8; ++_i) {                                        \
      const float* _src = w2q + (size_t)(row0 + n) * HQ +                   \
                          (hbase + (CB)) * 32 + (_i * 4 + g) * 4;           \
      gload_lds16(_src, (float*)(ldsv + w4 + (BUF) * 512 + _i * 64));       \
    }                                                                       \
  } while (0)

#define DN_HF(CB, H) do {                                                   \
    _Pragma("unroll")                                                       \
    for (int _k = 0; _k < 4; ++_k) {                                        \
      const float* _p = hf + (size_t)n * HQ + (hbase + (CB) + _k) * 32 + kb;\
      H[2 * _k]     = *(const float4*)_p;                                   \
      H[2 * _k + 1] = *(const float4*)(_p + 4);                             \
    }                                                                       \
  } while (0)

#define DN_COMP(CB, BUF, H, LO, HI) do {                                    \
    _Pragma("unroll")                                                       \
    for (int _kk = 0; _kk < 4; ++_kk) {                                     \
      if ((CB) + _kk >= (LO) && (CB) + _kk < (HI)) {                        \
        const int _u0 = _kk * 8 + 2 * g;                                    \
        const float4 _a  = *(const float4*)(ldsv + w4 + (BUF) * 512 +       \
                                            _u0 * 16 + n);                  \
        const float4 _b2 = *(const float4*)(ldsv + w4 + (BUF) * 512 +       \
                                            (_u0 + 1) * 16 + n);            \
        acc = __builtin_amdgcn_mfma_f32_16x16x32_bf16(cvt8(_a, _b2),        \
                  cvt8(H[2 * _kk], H[2 * _kk + 1]), acc, 0, 0, 0);          \
      }                                                                     \
    }                                                                       \
  } while (0)

__global__ __launch_bounds__(256) void k_down(const float* __restrict__ w2q,
                                              const float* __restrict__ b2,
                                              const float* __restrict__ ws,
                                              float* __restrict__ out) {
  __shared__ float4 ldsv[4096];
  __shared__ float red[1024];
  const int t = threadIdx.x, w = t >> 6, l = t & 63;
  const int tile = blockIdx.x >> 1, half = blockIdx.x & 1;
  const int row0 = tile * 16;
  const int hbase = half * 43;
  const int n = l & 15, g = l >> 4, kb = g * 8;
  const int w4 = w * 1024;
  const float* hf = ws + HF_OFF;

  const int wstart = (w == 0) ? 0 : (w == 1) ? 12 : (w == 2) ? 23 : 33;
  const int vlen   = (w == 0) ? 12 : (w == 1) ? 11 : 10;
  const int cb0 = wstart, cb1 = wstart + 4;
  const int cb2t = wstart + 8;
  const int cb2 = (cb2t > 39) ? 39 : cb2t;     // clamp staging in-bounds
  const int hi2 = wstart + vlen;

  f32x4 acc = {0.f, 0.f, 0.f, 0.f};
  float4 h0[8], h1[8], h2[8];

  DN_ISSUE(cb0, 0); SB;
  DN_HF(cb0, h0);   SB;
  DN_ISSUE(cb1, 1); SB;
  DN_HF(cb1, h1);   SB;
  WAITV(16); SB;                  // DMA0 + hf0 retired
  DN_COMP(cb0, 0, h0, 0, 9999);
  WAITL; SB;
  DN_ISSUE(cb2, 0); SB;
  DN_HF(cb2, h2);   SB;
  WAITV(16); SB;                  // DMA1 + hf1 retired
  DN_COMP(cb1, 1, h1, 0, 9999);
  WAITV(0); SB;
  DN_COMP(cb2, 0, h2, cb2t, hi2);

#pragma unroll
  for (int r = 0; r < 4; ++r) red[(w * 4 + r) * 64 + l] = acc[r];
  __syncthreads();
  if (w == 0) {
    const float t20 = ws[T2_OFF + 2 * n], t21 = ws[T2_OFF + 2 * n + 1];
    const int m4 = g * 4;
#pragma unroll
    for (int r = 0; r < 4; ++r) {
      float v = red[r * 64 + l] + red[(4 + r) * 64 + l] +
                red[(8 + r) * 64 + l] + red[(12 + r) * 64 + l];
      const int oo = row0 + m4 + r;
      if (half == 0)
        v += 0.5f * (t20 * b2[2 * oo] + t21 * b2[2 * oo + 1]);
      atomicAdd(&out[n * DMODEL + oo], v);
    }
  }
}

// ---------------------------------------------------------------------------
extern "C" void kernel_launch(void* const* d_in, const int* in_sizes, int n_in,
                              void* d_out, int out_size, void* d_ws, size_t ws_size,
                              hipStream_t stream) {
  const float* x   = (const float*)d_in[0];
  const float* w1q = (const float*)d_in[1];
  const float* a1  = (const float*)d_in[2];
  const float* b1  = (const float*)d_in[3];
  const float* w3q = (const float*)d_in[4];
  const float* a3  = (const float*)d_in[5];
  const float* b3  = (const float*)d_in[6];
  const float* w2q = (const float*)d_in[7];
  const float* a2  = (const float*)d_in[8];
  const float* b2  = (const float*)d_in[9];
  float* out = (float*)d_out;
  float* ws  = (float*)d_ws;

  k_prep1<<<64, 256, 0, stream>>>(x, a1, a3, ws, out);
  k_gateup<<<HID / 16, 256, 0, stream>>>(w1q, w3q, b1, b3, a2, ws);
  k_down<<<512, 256, 0, stream>>>(w2q, b2, ws, out);
}